// Round 4
// baseline (3803.542 us; speedup 1.0000x reference)
//
#include <hip/hip_runtime.h>

#define T_SEQ  1024
#define NBATCH 512
#define IN_DIM 16
#define HDIM   128
#define G4     (4 * HDIM)

typedef unsigned short ushort_t;
typedef __attribute__((ext_vector_type(8))) short bf16x8;
typedef __attribute__((ext_vector_type(4))) float f32x4;

#define MFMA(a, b, c) __builtin_amdgcn_mfma_f32_16x16x32_bf16((a), (b), (c), 0, 0, 0)

__device__ __forceinline__ float sigf(float x) {
  return __builtin_amdgcn_rcpf(1.0f + __expf(-x));
}
__device__ __forceinline__ float tanhf_fast(float x) {
  return 1.0f - 2.0f * __builtin_amdgcn_rcpf(1.0f + __expf(2.0f * x));
}
// round-to-nearest-even fp32 -> bf16 bits; also returns the bf16 value as fp32
__device__ __forceinline__ ushort_t bf16_rne(float f, float* back) {
  unsigned u = __float_as_uint(f);
  unsigned r = u + 0x7fffu + ((u >> 16) & 1u);
  ushort_t h = (ushort_t)(r >> 16);
  *back = __uint_as_float((unsigned)h << 16);
  return h;
}
__device__ __forceinline__ void split_bf16(float f, ushort_t* hi, ushort_t* lo) {
  float fhi, d;
  *hi = bf16_rne(f, &fhi);
  *lo = bf16_rne(f - fhi, &d);
}

// ---------------- prep: split weights into bf16 hi/lo ----------------
__global__ __launch_bounds__(256) void prep_weights(
    const float* __restrict__ Whh0, const float* __restrict__ Whh1,
    const float* __restrict__ Wih0,
    ushort_t* __restrict__ w0h, ushort_t* __restrict__ w0l,
    ushort_t* __restrict__ w1h, ushort_t* __restrict__ w1l,
    ushort_t* __restrict__ wxh, ushort_t* __restrict__ wxl)
{
  const int idx = blockIdx.x * 256 + threadIdx.x;
  if (idx < 512 * HDIM) {
    split_bf16(Whh0[idx], &w0h[idx], &w0l[idx]);
    split_bf16(Whh1[idx], &w1h[idx], &w1l[idx]);
  }
  if (idx < 512 * 32) {  // Wih0 zero-padded K=16 -> 32
    const int g = idx >> 5, k = idx & 31;
    const float f = (k < IN_DIM) ? Wih0[g * IN_DIM + k] : 0.0f;
    split_bf16(f, &wxh[idx], &wxl[idx]);
  }
}

// ---------------- Layer 0: persistent MFMA recurrent kernel ----------------
// 256 WGs x 512 threads (8 waves). WG owns batches {2w,2w+1} (M-rows 0,1 of a
// padded 16-row MFMA tile). Whh0/Wih0 hi/lo B-fragments live in VGPRs.
// A-fragment ds_reads are exec-masked to row<2: rows 2..15 of A feed only
// C-rows 2..15, which are never read -> garbage is fine (8x less LDS traffic).
__global__ __launch_bounds__(512, 2) void lstm_l0(
    const float* __restrict__ x,
    const ushort_t* __restrict__ Wh_hi, const ushort_t* __restrict__ Wh_lo,
    const ushort_t* __restrict__ Wx_hi, const ushort_t* __restrict__ Wx_lo,
    const float* __restrict__ bih, const float* __restrict__ bhh,
    float* __restrict__ h1state, float* __restrict__ c1state,
    float* __restrict__ h1buf, int t0, int Tc)
{
  const int tid  = threadIdx.x;
  const int wg   = blockIdx.x;
  const int lane = tid & 63;
  const int wv   = tid >> 6;      // wave 0..7, owns gates [wv*64, wv*64+64)
  const int row  = lane & 15;     // A-row / B-col / C-col
  const int kq   = lane >> 4;     // k quarter

  // persistent B fragments: 4 N-tiles x (4 h K-tiles + 1 x K-tile), hi+lo
  bf16x8 Bh[4][4], Bl[4][4], Bxh[4], Bxl[4];
#pragma unroll
  for (int i = 0; i < 4; ++i) {
    const int col = wv * 64 + i * 16 + row;
#pragma unroll
    for (int kt = 0; kt < 4; ++kt) {
      const int off = col * HDIM + kt * 32 + kq * 8;
      Bh[i][kt] = *(const bf16x8*)&Wh_hi[off];
      Bl[i][kt] = *(const bf16x8*)&Wh_lo[off];
    }
    const int xoff = col * 32 + kq * 8;
    Bxh[i] = *(const bf16x8*)&Wx_hi[xoff];
    Bxl[i] = *(const bf16x8*)&Wx_lo[xoff];
  }

  __shared__ __align__(16) ushort_t hfrag[2][2][136];  // [hi/lo][batch][k]
  __shared__ __align__(16) ushort_t xfrag[2][2][40];   // [hi/lo][batch][k] (k>=16 stays 0)
  __shared__ __align__(16) float xs[2][64][IN_DIM];    // fp32 x window
  __shared__ __align__(8)  float gs2[G4][2];           // gates x {batch0,batch1}

  const int bb = tid >> 7;   // update-phase batch (tid<256)
  const int j  = tid & 127;  // update-phase hidden idx
  float bz[4] = {0, 0, 0, 0};
  float c = 0.0f, hcur = 0.0f;
  const bf16x8 z8 = (bf16x8){0, 0, 0, 0, 0, 0, 0, 0};

  // zero xfrag once: K-pad region [16,32) must stay 0 (NaN*0 would contaminate)
  for (int idx = tid; idx < 2 * 2 * 40; idx += 512) ((ushort_t*)xfrag)[idx] = 0;
  // stage initial 64-step x window
  {
    const int tb = t0 & ~63;
    const int sb = tid >> 8;
    const int f  = (tid & 255) * 4;
    const int ts = f >> 4, ii = f & 15;
    *(float4*)&xs[sb][ts][ii] =
        *(const float4*)&x[((size_t)(wg * 2 + sb) * T_SEQ + (tb + ts)) * IN_DIM + ii];
  }
  __syncthreads();
  if (tid < 256) {
#pragma unroll
    for (int q = 0; q < 4; ++q) bz[q] = bih[q * 128 + j] + bhh[q * 128 + j];
    const int bg = wg * 2 + bb;
    hcur = h1state[(size_t)bg * HDIM + j];
    c    = c1state[(size_t)bg * HDIM + j];
    split_bf16(hcur, &hfrag[0][bb][j], &hfrag[1][bb][j]);
  }
  if (tid < 32) {
    const int b = tid >> 4, k = tid & 15;
    split_bf16(xs[b][t0 & 63][k], &xfrag[0][b][k], &xfrag[1][b][k]);
  }
  __syncthreads();

  for (int tt = 0; tt < Tc; ++tt) {
    const int t = t0 + tt;
    // ---- MFMA phase: gates = [h; x] . W^T (hi/lo 3-term) ----
    f32x4 acc[4];
#pragma unroll
    for (int i = 0; i < 4; ++i) acc[i] = (f32x4){0.f, 0.f, 0.f, 0.f};
#pragma unroll
    for (int kt = 0; kt < 4; ++kt) {
      bf16x8 ah = z8, al = z8;
      if (row < 2) {
        ah = *(const bf16x8*)&hfrag[0][row][kt * 32 + kq * 8];
        al = *(const bf16x8*)&hfrag[1][row][kt * 32 + kq * 8];
      }
#pragma unroll
      for (int i = 0; i < 4; ++i) acc[i] = MFMA(ah, Bh[i][kt], acc[i]);
#pragma unroll
      for (int i = 0; i < 4; ++i) acc[i] = MFMA(ah, Bl[i][kt], acc[i]);
#pragma unroll
      for (int i = 0; i < 4; ++i) acc[i] = MFMA(al, Bh[i][kt], acc[i]);
    }
    {
      bf16x8 axh = z8, axl = z8;
      if (row < 2) {
        axh = *(const bf16x8*)&xfrag[0][row][kq * 8];
        axl = *(const bf16x8*)&xfrag[1][row][kq * 8];
      }
#pragma unroll
      for (int i = 0; i < 4; ++i) acc[i] = MFMA(axh, Bxh[i], acc[i]);
#pragma unroll
      for (int i = 0; i < 4; ++i) acc[i] = MFMA(axh, Bxl[i], acc[i]);
#pragma unroll
      for (int i = 0; i < 4; ++i) acc[i] = MFMA(axl, Bxh[i], acc[i]);
    }
    if (kq == 0) {  // C rows 0,1 = batches
#pragma unroll
      for (int i = 0; i < 4; ++i) {
        const int g = wv * 64 + i * 16 + row;
        float2 v;
        v.x = acc[i][0];
        v.y = acc[i][1];
        *(float2*)&gs2[g][0] = v;
      }
    }
    __syncthreads();

    // ---- update phase ----
    const bool needStage = (((t + 1) & 63) == 0) && (t + 1 < T_SEQ);
    if (tid < 256) {
      const float zi = gs2[j][bb]       + bz[0];
      const float zf = gs2[128 + j][bb] + bz[1];
      const float zg = gs2[256 + j][bb] + bz[2];
      const float zo = gs2[384 + j][bb] + bz[3];
      const float ig = sigf(zi), fg = sigf(zf);
      const float gg = tanhf_fast(zg), og = sigf(zo);
      c = fg * c + ig * gg;
      hcur = og * tanhf_fast(c);
      split_bf16(hcur, &hfrag[0][bb][j], &hfrag[1][bb][j]);
      h1buf[((size_t)tt * NBATCH + (wg * 2 + bb)) * HDIM + j] = hcur;
    } else if (needStage) {
      const int u  = tid - 256;
      const int tb = t + 1;
#pragma unroll
      for (int q = 0; q < 2; ++q) {
        const int f  = (q * 256 + u) * 4;
        const int sb = f >> 10;
        const int ff = f & 1023;
        const int ts = ff >> 4, ii = ff & 15;
        *(float4*)&xs[sb][ts][ii] =
            *(const float4*)&x[((size_t)(wg * 2 + sb) * T_SEQ + (tb + ts)) * IN_DIM + ii];
      }
    }
    if (needStage) __syncthreads();
    if (tid < 32 && tt + 1 < Tc) {
      const int b = tid >> 4, k = tid & 15;
      split_bf16(xs[b][(t + 1) & 63][k], &xfrag[0][b][k], &xfrag[1][b][k]);
    }
    __syncthreads();
  }

  if (tid < 256) {
    const int bg = wg * 2 + bb;
    h1state[(size_t)bg * HDIM + j] = hcur;
    c1state[(size_t)bg * HDIM + j] = c;
  }
}

// ---------------- gx1 GEMM (unchanged) ----------------
#define BM 128
#define BN 64
#define BK 32

__global__ __launch_bounds__(256, 4) void gemm_gx1(
    const float* __restrict__ h1buf, const float* __restrict__ Wih1,
    const float* __restrict__ bih1, const float* __restrict__ bhh1,
    float* __restrict__ gx1buf)
{
  const int u  = threadIdx.x;
  const int tx = u & 15;
  const int ty = u >> 4;
  const size_t m0 = (size_t)(blockIdx.x >> 3) * BM;
  const int    n0 = (blockIdx.x & 7) * BN;

  __shared__ __align__(16) float As[BK][132];
  __shared__ __align__(16) float Bs[BK][68];

  float acc[8][4] = {};

  for (int k0 = 0; k0 < HDIM; k0 += BK) {
    __syncthreads();
#pragma unroll
    for (int jj = 0; jj < 4; ++jj) {
      const int f  = jj * 256 + u;
      const int m  = f >> 3;
      const int k4 = (f & 7) * 4;
      const float4 v = *(const float4*)&h1buf[(m0 + m) * HDIM + k0 + k4];
      As[k4 + 0][m] = v.x; As[k4 + 1][m] = v.y;
      As[k4 + 2][m] = v.z; As[k4 + 3][m] = v.w;
    }
#pragma unroll
    for (int jj = 0; jj < 2; ++jj) {
      const int f  = jj * 256 + u;
      const int g  = f >> 3;
      const int k4 = (f & 7) * 4;
      const float4 v = *(const float4*)&Wih1[(size_t)(n0 + g) * HDIM + k0 + k4];
      Bs[k4 + 0][g] = v.x; Bs[k4 + 1][g] = v.y;
      Bs[k4 + 2][g] = v.z; Bs[k4 + 3][g] = v.w;
    }
    __syncthreads();

#pragma unroll 4
    for (int k = 0; k < BK; ++k) {
      const float4 b  = *(const float4*)&Bs[k][tx * 4];
      const float4 a0 = *(const float4*)&As[k][ty * 8];
      const float4 a1 = *(const float4*)&As[k][ty * 8 + 4];
      const float av[8] = {a0.x, a0.y, a0.z, a0.w, a1.x, a1.y, a1.z, a1.w};
      const float bv[4] = {b.x, b.y, b.z, b.w};
#pragma unroll
      for (int i = 0; i < 8; ++i)
#pragma unroll
        for (int q = 0; q < 4; ++q)
          acc[i][q] += av[i] * bv[q];
    }
  }

  const float4 b1 = *(const float4*)&bih1[n0 + tx * 4];
  const float4 b2 = *(const float4*)&bhh1[n0 + tx * 4];
  const float bias[4] = {b1.x + b2.x, b1.y + b2.y, b1.z + b2.z, b1.w + b2.w};

#pragma unroll
  for (int i = 0; i < 8; ++i) {
    float4 o;
    o.x = acc[i][0] + bias[0];
    o.y = acc[i][1] + bias[1];
    o.z = acc[i][2] + bias[2];
    o.w = acc[i][3] + bias[3];
    *(float4*)&gx1buf[(m0 + ty * 8 + i) * G4 + n0 + tx * 4] = o;
  }
}

// ---------------- Layer 1 (MFMA) + fused FC ----------------
__global__ __launch_bounds__(512, 2) void lstm_l1(
    const float* __restrict__ gx1buf,
    const ushort_t* __restrict__ Wh_hi, const ushort_t* __restrict__ Wh_lo,
    const float* __restrict__ Wfc, const float* __restrict__ bfc,
    float* __restrict__ h2state, float* __restrict__ c2state,
    float* __restrict__ out, int t0, int Tc)
{
  const int tid  = threadIdx.x;
  const int wg   = blockIdx.x;
  const int lane = tid & 63;
  const int wv   = tid >> 6;
  const int row  = lane & 15;
  const int kq   = lane >> 4;

  bf16x8 Bh[4][4], Bl[4][4];
#pragma unroll
  for (int i = 0; i < 4; ++i) {
    const int col = wv * 64 + i * 16 + row;
#pragma unroll
    for (int kt = 0; kt < 4; ++kt) {
      const int off = col * HDIM + kt * 32 + kq * 8;
      Bh[i][kt] = *(const bf16x8*)&Wh_hi[off];
      Bl[i][kt] = *(const bf16x8*)&Wh_lo[off];
    }
  }

  __shared__ __align__(16) ushort_t hfrag[2][2][136];
  __shared__ __align__(8)  float gs2[G4][2];
  __shared__ float pl[4];

  const int bb = tid >> 7;
  const int j  = tid & 127;
  float c = 0.0f, hcur = 0.0f, wfc = 0.0f;
  const float bfcv = bfc[0];
  const bf16x8 z8 = (bf16x8){0, 0, 0, 0, 0, 0, 0, 0};

  float zc[4] = {0, 0, 0, 0};
  if (tid < 256) {
    const int bg = wg * 2 + bb;
    hcur = h2state[(size_t)bg * HDIM + j];
    c    = c2state[(size_t)bg * HDIM + j];
    wfc  = Wfc[j];
    split_bf16(hcur, &hfrag[0][bb][j], &hfrag[1][bb][j]);
#pragma unroll
    for (int q = 0; q < 4; ++q)
      zc[q] = gx1buf[((size_t)0 * NBATCH + wg * 2 + bb) * G4 + q * 128 + j];
  }
  __syncthreads();

  for (int tt = 0; tt < Tc; ++tt) {
    f32x4 acc[4];
#pragma unroll
    for (int i = 0; i < 4; ++i) acc[i] = (f32x4){0.f, 0.f, 0.f, 0.f};
#pragma unroll
    for (int kt = 0; kt < 4; ++kt) {
      bf16x8 ah = z8, al = z8;
      if (row < 2) {
        ah = *(const bf16x8*)&hfrag[0][row][kt * 32 + kq * 8];
        al = *(const bf16x8*)&hfrag[1][row][kt * 32 + kq * 8];
      }
#pragma unroll
      for (int i = 0; i < 4; ++i) acc[i] = MFMA(ah, Bh[i][kt], acc[i]);
#pragma unroll
      for (int i = 0; i < 4; ++i) acc[i] = MFMA(ah, Bl[i][kt], acc[i]);
#pragma unroll
      for (int i = 0; i < 4; ++i) acc[i] = MFMA(al, Bh[i][kt], acc[i]);
    }
    if (kq == 0) {
#pragma unroll
      for (int i = 0; i < 4; ++i) {
        const int g = wv * 64 + i * 16 + row;
        float2 v;
        v.x = acc[i][0];
        v.y = acc[i][1];
        *(float2*)&gs2[g][0] = v;
      }
    }
    __syncthreads();

    if (tid < 256) {
      const float zi = gs2[j][bb]       + zc[0];
      const float zf = gs2[128 + j][bb] + zc[1];
      const float zg = gs2[256 + j][bb] + zc[2];
      const float zo = gs2[384 + j][bb] + zc[3];
      const float ig = sigf(zi), fg = sigf(zf);
      const float gg = tanhf_fast(zg), og = sigf(zo);
      c = fg * c + ig * gg;
      hcur = og * tanhf_fast(c);
      split_bf16(hcur, &hfrag[0][bb][j], &hfrag[1][bb][j]);
      if (tt + 1 < Tc) {
#pragma unroll
        for (int q = 0; q < 4; ++q)
          zc[q] = gx1buf[((size_t)(tt + 1) * NBATCH + wg * 2 + bb) * G4 + q * 128 + j];
      }
      float p = fmaxf(hcur, 0.0f) * wfc;
#pragma unroll
      for (int off = 32; off; off >>= 1) p += __shfl_down(p, off);
      if ((tid & 63) == 0) pl[tid >> 6] = p;
    }
    __syncthreads();

    if (tid < 2) {
      const float o = pl[2 * tid] + pl[2 * tid + 1] + bfcv;
      out[(size_t)(wg * 2 + tid) * T_SEQ + (t0 + tt)] = fmaxf(o, 0.0f);
    }
  }

  if (tid < 256) {
    const int bg = wg * 2 + bb;
    h2state[(size_t)bg * HDIM + j] = hcur;
    c2state[(size_t)bg * HDIM + j] = c;
  }
}

extern "C" void kernel_launch(void* const* d_in, const int* in_sizes, int n_in,
                              void* d_out, int out_size, void* d_ws, size_t ws_size,
                              hipStream_t stream)
{
  const float* x    = (const float*)d_in[0];
  const float* Wih0 = (const float*)d_in[1];
  const float* Whh0 = (const float*)d_in[2];
  const float* bih0 = (const float*)d_in[3];
  const float* bhh0 = (const float*)d_in[4];
  const float* Wih1 = (const float*)d_in[5];
  const float* Whh1 = (const float*)d_in[6];
  const float* bih1 = (const float*)d_in[7];
  const float* bhh1 = (const float*)d_in[8];
  const float* Wfc  = (const float*)d_in[9];
  const float* bfc  = (const float*)d_in[10];
  float* out = (float*)d_out;

  const size_t stateN = (size_t)NBATCH * HDIM;  // 65536
  float* h1s = (float*)d_ws;
  float* c1s = h1s + stateN;
  float* h2s = c1s + stateN;
  float* c2s = h2s + stateN;
  ushort_t* w0h = (ushort_t*)(c2s + stateN);
  ushort_t* w0l = w0h + stateN;
  ushort_t* w1h = w0l + stateN;
  ushort_t* w1l = w1h + stateN;
  ushort_t* wxh = w1l + stateN;
  ushort_t* wxl = wxh + 512 * 32;
  float* h1buf  = (float*)(wxl + 512 * 32);
  const size_t fixedBytes =
      4 * stateN * sizeof(float) + (4 * stateN + 2 * 512 * 32) * sizeof(ushort_t);

  int Tc = 128;
  while (Tc > 1) {
    const size_t need =
        fixedBytes + (size_t)Tc * NBATCH * (HDIM + G4) * sizeof(float);
    if (need <= ws_size) break;
    Tc >>= 1;
  }
  float* gx1buf = h1buf + (size_t)Tc * NBATCH * HDIM;

  hipLaunchKernelGGL(prep_weights, dim3(256), dim3(256), 0, stream,
                     Whh0, Whh1, Wih0, w0h, w0l, w1h, w1l, wxh, wxl);
  hipMemsetAsync(d_ws, 0, 4 * stateN * sizeof(float), stream);

  for (int t0 = 0; t0 < T_SEQ; t0 += Tc) {
    hipLaunchKernelGGL(lstm_l0, dim3(NBATCH / 2), dim3(512), 0, stream,
                       x, w0h, w0l, wxh, wxl, bih0, bhh0, h1s, c1s, h1buf, t0, Tc);
    hipLaunchKernelGGL(gemm_gx1, dim3((Tc * NBATCH / BM) * (G4 / BN)),
                       dim3(256), 0, stream,
                       h1buf, Wih1, bih1, bhh1, gx1buf);
    hipLaunchKernelGGL(lstm_l1, dim3(NBATCH / 2), dim3(512), 0, stream,
                       gx1buf, w1h, w1l, Wfc, bfc, h2s, c2s, out, t0, Tc);
  }
}

// Round 6
// 3235.565 us; speedup vs baseline: 1.1755x; 1.1755x over previous
//
#include <hip/hip_runtime.h>

#define T_SEQ  1024
#define NBATCH 512
#define IN_DIM 16
#define HDIM   128
#define G4     (4 * HDIM)

typedef unsigned short ushort_t;
typedef __attribute__((ext_vector_type(8))) _Float16 f16x8;
typedef __attribute__((ext_vector_type(4))) float f32x4;

#define MFMA16(a, b, c) __builtin_amdgcn_mfma_f32_16x16x32_f16((a), (b), (c), 0, 0, 0)

__device__ __forceinline__ float sigf(float x) {
  return __builtin_amdgcn_rcpf(1.0f + __expf(-x));
}
__device__ __forceinline__ float tanhf_fast(float x) {
  return 1.0f - 2.0f * __builtin_amdgcn_rcpf(1.0f + __expf(2.0f * x));
}

// fp32 -> fp16 bits, round-to-nearest-even, pure bit ops (no __half needed).
__device__ __forceinline__ ushort_t f16_bits(float f) {
  unsigned u = __float_as_uint(f);
  const unsigned sign = (u >> 16) & 0x8000u;
  u &= 0x7fffffffu;
  if (u >= 0x47800000u) return (ushort_t)(sign | 0x7c00u);  // overflow -> inf
  if (u < 0x38800000u) {                                    // denormal/zero
    if (u < 0x33000000u) return (ushort_t)sign;             // underflow -> 0
    const int shift = 126 - (int)(u >> 23);                 // 0..23
    unsigned m = (u & 0x7fffffu) | 0x800000u;
    const unsigned d = m >> (shift + 13);
    const unsigned rem = m & ((1u << (shift + 13)) - 1u);
    const unsigned half = 1u << (shift + 12);
    unsigned r = d + ((rem > half) || (rem == half && (d & 1u)) ? 1u : 0u);
    return (ushort_t)(sign | r);
  }
  // normal range: rebias exponent, RNE on 13 dropped bits
  const unsigned m13 = u & 0x1fffu;
  unsigned h = ((u - 0x38000000u) >> 13);
  h += (m13 > 0x1000u) || (m13 == 0x1000u && (h & 1u)) ? 1u : 0u;
  return (ushort_t)(sign | h);
}
__device__ __forceinline__ float f16_back(ushort_t h) {
  const unsigned sign = ((unsigned)h & 0x8000u) << 16;
  const unsigned em = (unsigned)h & 0x7fffu;
  if (em == 0) return __uint_as_float(sign);
  unsigned u;
  if (em >= 0x0400u) {
    u = sign | ((em + 0x1c000u) << 13);  // normal
  } else {
    // denormal fp16 -> normal fp32
    int e = -1;
    unsigned m = em;
    while (!(m & 0x0400u)) { m <<= 1; --e; }
    u = sign | ((unsigned)(127 - 15 + e) << 23) | ((m & 0x3ffu) << 13);
  }
  return __uint_as_float(u);
}
__device__ __forceinline__ void split_f16(float f, ushort_t* hi, ushort_t* lo) {
  const ushort_t h = f16_bits(f);
  *hi = h;
  *lo = f16_bits(f - f16_back(h));
}

// ---------------- prep: split weights into fp16 hi/lo ----------------
__global__ __launch_bounds__(256) void prep_weights(
    const float* __restrict__ Whh0, const float* __restrict__ Whh1,
    const float* __restrict__ Wih0,
    ushort_t* __restrict__ w0h, ushort_t* __restrict__ w0l,
    ushort_t* __restrict__ w1h, ushort_t* __restrict__ w1l,
    ushort_t* __restrict__ wxh, ushort_t* __restrict__ wxl)
{
  const int idx = blockIdx.x * 256 + threadIdx.x;
  if (idx < 512 * HDIM) {
    split_f16(Whh0[idx], &w0h[idx], &w0l[idx]);
    split_f16(Whh1[idx], &w1h[idx], &w1l[idx]);
  }
  if (idx < 512 * 32) {  // Wih0 zero-padded K=16 -> 32
    const int g = idx >> 5, k = idx & 31;
    const float f = (k < IN_DIM) ? Wih0[g * IN_DIM + k] : 0.0f;
    split_f16(f, &wxh[idx], &wxl[idx]);
  }
}

// ---------------- Layer 0: persistent MFMA recurrent kernel ----------------
// 256 WGs x 512 threads (8 waves). WG owns batches {2w,2w+1} (M-rows 0,1 of a
// padded 16-row MFMA tile; rows 2..15 of C are never read, so ALL lanes read
// A from row (lane&1): 8-lane broadcast, conflict-free, no divergence).
__global__ __launch_bounds__(512, 2) void lstm_l0(
    const float* __restrict__ x,
    const ushort_t* __restrict__ Wh_hi, const ushort_t* __restrict__ Wh_lo,
    const ushort_t* __restrict__ Wx_hi, const ushort_t* __restrict__ Wx_lo,
    const float* __restrict__ bih, const float* __restrict__ bhh,
    float* __restrict__ h1state, float* __restrict__ c1state,
    float* __restrict__ h1buf, int t0, int Tc)
{
  const int tid  = threadIdx.x;
  const int wg   = blockIdx.x;
  const int lane = tid & 63;
  const int wv   = tid >> 6;      // wave 0..7, owns gates [wv*64, wv*64+64)
  const int row  = lane & 15;     // B-col / C-col
  const int arow = lane & 1;      // broadcast A-row (real batches only)
  const int kq   = lane >> 4;     // k quarter

  // persistent B fragments: 4 N-tiles x (4 h K-tiles + 1 x K-tile), hi+lo fp16
  f16x8 Bh[4][4], Bl[4][4], Bxh[4], Bxl[4];
#pragma unroll
  for (int i = 0; i < 4; ++i) {
    const int col = wv * 64 + i * 16 + row;
#pragma unroll
    for (int kt = 0; kt < 4; ++kt) {
      const int off = col * HDIM + kt * 32 + kq * 8;
      Bh[i][kt] = *(const f16x8*)&Wh_hi[off];
      Bl[i][kt] = *(const f16x8*)&Wh_lo[off];
    }
    const int xoff = col * 32 + kq * 8;
    Bxh[i] = *(const f16x8*)&Wx_hi[xoff];
    Bxl[i] = *(const f16x8*)&Wx_lo[xoff];
  }

  __shared__ __align__(16) ushort_t hfrag[2][136];   // [batch][k] fp16 h
  __shared__ __align__(16) ushort_t xfrag[2][40];    // [batch][k] fp16 x (k>=16 == 0)
  __shared__ __align__(16) float xs[2][64][IN_DIM];  // fp32 x window
  __shared__ __align__(8)  float gs2[G4][2];         // gates x {batch0,batch1}

  const int bb = tid >> 7;   // update-phase batch (tid<256)
  const int j  = tid & 127;  // update-phase hidden idx
  float bz[4] = {0, 0, 0, 0};
  float c = 0.0f, hcur = 0.0f;

  // zero xfrag once: K-pad region [16,32) must stay 0
  for (int idx = tid; idx < 2 * 40; idx += 512) ((ushort_t*)xfrag)[idx] = 0;
  // stage initial 64-step x window
  {
    const int tb = t0 & ~63;
    const int sb = tid >> 8;
    const int f  = (tid & 255) * 4;
    const int ts = f >> 4, ii = f & 15;
    *(float4*)&xs[sb][ts][ii] =
        *(const float4*)&x[((size_t)(wg * 2 + sb) * T_SEQ + (tb + ts)) * IN_DIM + ii];
  }
  __syncthreads();
  if (tid < 256) {
#pragma unroll
    for (int q = 0; q < 4; ++q) bz[q] = bih[q * 128 + j] + bhh[q * 128 + j];
    const int bg = wg * 2 + bb;
    hcur = h1state[(size_t)bg * HDIM + j];
    c    = c1state[(size_t)bg * HDIM + j];
    hfrag[bb][j] = f16_bits(hcur);
  }
  if (tid < 32) {
    const int b = tid >> 4, k = tid & 15;
    xfrag[b][k] = f16_bits(xs[b][t0 & 63][k]);
  }
  __syncthreads();

  for (int tt = 0; tt < Tc; ++tt) {
    const int t = t0 + tt;
    // ---- MFMA phase: gates = [h; x] . W^T (fp16 2-term) ----
    f32x4 acc[4];
#pragma unroll
    for (int i = 0; i < 4; ++i) acc[i] = (f32x4){0.f, 0.f, 0.f, 0.f};
#pragma unroll
    for (int kt = 0; kt < 4; ++kt) {
      const f16x8 ah = *(const f16x8*)&hfrag[arow][kt * 32 + kq * 8];
#pragma unroll
      for (int i = 0; i < 4; ++i) acc[i] = MFMA16(ah, Bh[i][kt], acc[i]);
#pragma unroll
      for (int i = 0; i < 4; ++i) acc[i] = MFMA16(ah, Bl[i][kt], acc[i]);
    }
    {
      const f16x8 ax = *(const f16x8*)&xfrag[arow][kq * 8];
#pragma unroll
      for (int i = 0; i < 4; ++i) acc[i] = MFMA16(ax, Bxh[i], acc[i]);
#pragma unroll
      for (int i = 0; i < 4; ++i) acc[i] = MFMA16(ax, Bxl[i], acc[i]);
    }
    if (kq == 0) {  // C rows 0,1 = batches
#pragma unroll
      for (int i = 0; i < 4; ++i) {
        const int g = wv * 64 + i * 16 + row;
        float2 v;
        v.x = acc[i][0];
        v.y = acc[i][1];
        *(float2*)&gs2[g][0] = v;
      }
    }
    __syncthreads();

    // ---- update phase ----
    const bool needStage = (((t + 1) & 63) == 0) && (t + 1 < T_SEQ);
    if (tid < 256) {
      const float zi = gs2[j][bb]       + bz[0];
      const float zf = gs2[128 + j][bb] + bz[1];
      const float zg = gs2[256 + j][bb] + bz[2];
      const float zo = gs2[384 + j][bb] + bz[3];
      const float ig = sigf(zi), fg = sigf(zf);
      const float gg = tanhf_fast(zg), og = sigf(zo);
      c = fg * c + ig * gg;
      hcur = og * tanhf_fast(c);
      hfrag[bb][j] = f16_bits(hcur);
      h1buf[((size_t)tt * NBATCH + (wg * 2 + bb)) * HDIM + j] = hcur;
    } else if (needStage) {
      const int u  = tid - 256;
      const int tb = t + 1;
#pragma unroll
      for (int q = 0; q < 2; ++q) {
        const int f  = (q * 256 + u) * 4;
        const int sb = f >> 10;
        const int ff = f & 1023;
        const int ts = ff >> 4, ii = ff & 15;
        *(float4*)&xs[sb][ts][ii] =
            *(const float4*)&x[((size_t)(wg * 2 + sb) * T_SEQ + (tb + ts)) * IN_DIM + ii];
      }
    }
    if (needStage) __syncthreads();
    if (tid < 32 && tt + 1 < Tc) {
      const int b = tid >> 4, k = tid & 15;
      xfrag[b][k] = f16_bits(xs[b][(t + 1) & 63][k]);
    }
    __syncthreads();
  }

  if (tid < 256) {
    const int bg = wg * 2 + bb;
    h1state[(size_t)bg * HDIM + j] = hcur;
    c1state[(size_t)bg * HDIM + j] = c;
  }
}

// ---------------- gx1 GEMM (unchanged) ----------------
#define BM 128
#define BN 64
#define BK 32

__global__ __launch_bounds__(256, 4) void gemm_gx1(
    const float* __restrict__ h1buf, const float* __restrict__ Wih1,
    const float* __restrict__ bih1, const float* __restrict__ bhh1,
    float* __restrict__ gx1buf)
{
  const int u  = threadIdx.x;
  const int tx = u & 15;
  const int ty = u >> 4;
  const size_t m0 = (size_t)(blockIdx.x >> 3) * BM;
  const int    n0 = (blockIdx.x & 7) * BN;

  __shared__ __align__(16) float As[BK][132];
  __shared__ __align__(16) float Bs[BK][68];

  float acc[8][4] = {};

  for (int k0 = 0; k0 < HDIM; k0 += BK) {
    __syncthreads();
#pragma unroll
    for (int jj = 0; jj < 4; ++jj) {
      const int f  = jj * 256 + u;
      const int m  = f >> 3;
      const int k4 = (f & 7) * 4;
      const float4 v = *(const float4*)&h1buf[(m0 + m) * HDIM + k0 + k4];
      As[k4 + 0][m] = v.x; As[k4 + 1][m] = v.y;
      As[k4 + 2][m] = v.z; As[k4 + 3][m] = v.w;
    }
#pragma unroll
    for (int jj = 0; jj < 2; ++jj) {
      const int f  = jj * 256 + u;
      const int g  = f >> 3;
      const int k4 = (f & 7) * 4;
      const float4 v = *(const float4*)&Wih1[(size_t)(n0 + g) * HDIM + k0 + k4];
      Bs[k4 + 0][g] = v.x; Bs[k4 + 1][g] = v.y;
      Bs[k4 + 2][g] = v.z; Bs[k4 + 3][g] = v.w;
    }
    __syncthreads();

#pragma unroll 4
    for (int k = 0; k < BK; ++k) {
      const float4 b  = *(const float4*)&Bs[k][tx * 4];
      const float4 a0 = *(const float4*)&As[k][ty * 8];
      const float4 a1 = *(const float4*)&As[k][ty * 8 + 4];
      const float av[8] = {a0.x, a0.y, a0.z, a0.w, a1.x, a1.y, a1.z, a1.w};
      const float bv[4] = {b.x, b.y, b.z, b.w};
#pragma unroll
      for (int i = 0; i < 8; ++i)
#pragma unroll
        for (int q = 0; q < 4; ++q)
          acc[i][q] += av[i] * bv[q];
    }
  }

  const float4 b1 = *(const float4*)&bih1[n0 + tx * 4];
  const float4 b2 = *(const float4*)&bhh1[n0 + tx * 4];
  const float bias[4] = {b1.x + b2.x, b1.y + b2.y, b1.z + b2.z, b1.w + b2.w};

#pragma unroll
  for (int i = 0; i < 8; ++i) {
    float4 o;
    o.x = acc[i][0] + bias[0];
    o.y = acc[i][1] + bias[1];
    o.z = acc[i][2] + bias[2];
    o.w = acc[i][3] + bias[3];
    *(float4*)&gx1buf[(m0 + ty * 8 + i) * G4 + n0 + tx * 4] = o;
  }
}

// ---------------- Layer 1 (MFMA) + fused FC ----------------
__global__ __launch_bounds__(512, 2) void lstm_l1(
    const float* __restrict__ gx1buf,
    const ushort_t* __restrict__ Wh_hi, const ushort_t* __restrict__ Wh_lo,
    const float* __restrict__ Wfc, const float* __restrict__ bfc,
    float* __restrict__ h2state, float* __restrict__ c2state,
    float* __restrict__ out, int t0, int Tc)
{
  const int tid  = threadIdx.x;
  const int wg   = blockIdx.x;
  const int lane = tid & 63;
  const int wv   = tid >> 6;
  const int row  = lane & 15;
  const int arow = lane & 1;
  const int kq   = lane >> 4;

  f16x8 Bh[4][4], Bl[4][4];
#pragma unroll
  for (int i = 0; i < 4; ++i) {
    const int col = wv * 64 + i * 16 + row;
#pragma unroll
    for (int kt = 0; kt < 4; ++kt) {
      const int off = col * HDIM + kt * 32 + kq * 8;
      Bh[i][kt] = *(const f16x8*)&Wh_hi[off];
      Bl[i][kt] = *(const f16x8*)&Wh_lo[off];
    }
  }

  __shared__ __align__(16) ushort_t hfrag[2][136];
  __shared__ __align__(8)  float gs2[G4][2];
  __shared__ float pl[4];

  const int bb = tid >> 7;
  const int j  = tid & 127;
  float c = 0.0f, hcur = 0.0f, wfc = 0.0f;
  const float bfcv = bfc[0];

  float zc[4] = {0, 0, 0, 0};
  if (tid < 256) {
    const int bg = wg * 2 + bb;
    hcur = h2state[(size_t)bg * HDIM + j];
    c    = c2state[(size_t)bg * HDIM + j];
    wfc  = Wfc[j];
    hfrag[bb][j] = f16_bits(hcur);
#pragma unroll
    for (int q = 0; q < 4; ++q)
      zc[q] = gx1buf[((size_t)0 * NBATCH + wg * 2 + bb) * G4 + q * 128 + j];
  }
  __syncthreads();

  for (int tt = 0; tt < Tc; ++tt) {
    f32x4 acc[4];
#pragma unroll
    for (int i = 0; i < 4; ++i) acc[i] = (f32x4){0.f, 0.f, 0.f, 0.f};
#pragma unroll
    for (int kt = 0; kt < 4; ++kt) {
      const f16x8 ah = *(const f16x8*)&hfrag[arow][kt * 32 + kq * 8];
#pragma unroll
      for (int i = 0; i < 4; ++i) acc[i] = MFMA16(ah, Bh[i][kt], acc[i]);
#pragma unroll
      for (int i = 0; i < 4; ++i) acc[i] = MFMA16(ah, Bl[i][kt], acc[i]);
    }
    if (kq == 0) {
#pragma unroll
      for (int i = 0; i < 4; ++i) {
        const int g = wv * 64 + i * 16 + row;
        float2 v;
        v.x = acc[i][0];
        v.y = acc[i][1];
        *(float2*)&gs2[g][0] = v;
      }
    }
    __syncthreads();

    if (tid < 256) {
      const float zi = gs2[j][bb]       + zc[0];
      const float zf = gs2[128 + j][bb] + zc[1];
      const float zg = gs2[256 + j][bb] + zc[2];
      const float zo = gs2[384 + j][bb] + zc[3];
      const float ig = sigf(zi), fg = sigf(zf);
      const float gg = tanhf_fast(zg), og = sigf(zo);
      c = fg * c + ig * gg;
      hcur = og * tanhf_fast(c);
      hfrag[bb][j] = f16_bits(hcur);
      if (tt + 1 < Tc) {
#pragma unroll
        for (int q = 0; q < 4; ++q)
          zc[q] = gx1buf[((size_t)(tt + 1) * NBATCH + wg * 2 + bb) * G4 + q * 128 + j];
      }
      float p = fmaxf(hcur, 0.0f) * wfc;
#pragma unroll
      for (int off = 32; off; off >>= 1) p += __shfl_down(p, off);
      if ((tid & 63) == 0) pl[tid >> 6] = p;
    }
    __syncthreads();

    if (tid < 2) {
      const float o = pl[2 * tid] + pl[2 * tid + 1] + bfcv;
      out[(size_t)(wg * 2 + tid) * T_SEQ + (t0 + tt)] = fmaxf(o, 0.0f);
    }
  }

  if (tid < 256) {
    const int bg = wg * 2 + bb;
    h2state[(size_t)bg * HDIM + j] = hcur;
    c2state[(size_t)bg * HDIM + j] = c;
  }
}

extern "C" void kernel_launch(void* const* d_in, const int* in_sizes, int n_in,
                              void* d_out, int out_size, void* d_ws, size_t ws_size,
                              hipStream_t stream)
{
  const float* x    = (const float*)d_in[0];
  const float* Wih0 = (const float*)d_in[1];
  const float* Whh0 = (const float*)d_in[2];
  const float* bih0 = (const float*)d_in[3];
  const float* bhh0 = (const float*)d_in[4];
  const float* Wih1 = (const float*)d_in[5];
  const float* Whh1 = (const float*)d_in[6];
  const float* bih1 = (const float*)d_in[7];
  const float* bhh1 = (const float*)d_in[8];
  const float* Wfc  = (const float*)d_in[9];
  const float* bfc  = (const float*)d_in[10];
  float* out = (float*)d_out;

  const size_t stateN = (size_t)NBATCH * HDIM;  // 65536
  float* h1s = (float*)d_ws;
  float* c1s = h1s + stateN;
  float* h2s = c1s + stateN;
  float* c2s = h2s + stateN;
  ushort_t* w0h = (ushort_t*)(c2s + stateN);
  ushort_t* w0l = w0h + stateN;
  ushort_t* w1h = w0l + stateN;
  ushort_t* w1l = w1h + stateN;
  ushort_t* wxh = w1l + stateN;
  ushort_t* wxl = wxh + 512 * 32;
  float* h1buf  = (float*)(wxl + 512 * 32);
  const size_t fixedBytes =
      4 * stateN * sizeof(float) + (4 * stateN + 2 * 512 * 32) * sizeof(ushort_t);

  int Tc = 128;
  while (Tc > 1) {
    const size_t need =
        fixedBytes + (size_t)Tc * NBATCH * (HDIM + G4) * sizeof(float);
    if (need <= ws_size) break;
    Tc >>= 1;
  }
  float* gx1buf = h1buf + (size_t)Tc * NBATCH * HDIM;

  hipLaunchKernelGGL(prep_weights, dim3(256), dim3(256), 0, stream,
                     Whh0, Whh1, Wih0, w0h, w0l, w1h, w1l, wxh, wxl);
  (void)hipMemsetAsync(d_ws, 0, 4 * stateN * sizeof(float), stream);

  for (int t0 = 0; t0 < T_SEQ; t0 += Tc) {
    hipLaunchKernelGGL(lstm_l0, dim3(NBATCH / 2), dim3(512), 0, stream,
                       x, w0h, w0l, wxh, wxl, bih0, bhh0, h1s, c1s, h1buf, t0, Tc);
    hipLaunchKernelGGL(gemm_gx1, dim3((Tc * NBATCH / BM) * (G4 / BN)),
                       dim3(256), 0, stream,
                       h1buf, Wih1, bih1, bhh1, gx1buf);
    hipLaunchKernelGGL(lstm_l1, dim3(NBATCH / 2), dim3(512), 0, stream,
                       gx1buf, w1h, w1l, Wfc, bfc, h2s, c2s, out, t0, Tc);
  }
}

// Round 7
// 2692.684 us; speedup vs baseline: 1.4125x; 1.2016x over previous
//
#include <hip/hip_runtime.h>

#define T_SEQ  1024
#define NBATCH 512
#define IN_DIM 16
#define HDIM   128
#define G4     (4 * HDIM)

typedef unsigned short ushort_t;
typedef __attribute__((ext_vector_type(8))) _Float16 f16x8;
typedef __attribute__((ext_vector_type(4))) float f32x4;

#define MFMA16(a, b, c) __builtin_amdgcn_mfma_f32_16x16x32_f16((a), (b), (c), 0, 0, 0)

__device__ __forceinline__ float sigf(float x) {
  return __builtin_amdgcn_rcpf(1.0f + __expf(-x));
}
__device__ __forceinline__ float tanhf_fast(float x) {
  return 1.0f - 2.0f * __builtin_amdgcn_rcpf(1.0f + __expf(2.0f * x));
}
// fp32 -> fp16 via native conversion (single v_cvt_f16_f32, RNE)
__device__ __forceinline__ ushort_t f16_bits(float f) {
  const _Float16 h = (_Float16)f;
  return __builtin_bit_cast(unsigned short, h);
}
__device__ __forceinline__ void split_f16(float f, ushort_t* hi, ushort_t* lo) {
  const _Float16 h = (_Float16)f;
  *hi = __builtin_bit_cast(unsigned short, h);
  const _Float16 l = (_Float16)(f - (float)h);
  *lo = __builtin_bit_cast(unsigned short, l);
}

// ---------------- prep: split weights into fp16 hi/lo ----------------
__global__ __launch_bounds__(256) void prep_weights(
    const float* __restrict__ Whh0, const float* __restrict__ Whh1,
    const float* __restrict__ Wih0, const float* __restrict__ Wih1,
    ushort_t* __restrict__ w0h, ushort_t* __restrict__ w0l,
    ushort_t* __restrict__ w1h, ushort_t* __restrict__ w1l,
    ushort_t* __restrict__ wxh, ushort_t* __restrict__ wxl,
    ushort_t* __restrict__ wi1h, ushort_t* __restrict__ wi1l)
{
  const int idx = blockIdx.x * 256 + threadIdx.x;
  if (idx < 512 * HDIM) {
    split_f16(Whh0[idx], &w0h[idx], &w0l[idx]);
    split_f16(Whh1[idx], &w1h[idx], &w1l[idx]);
    split_f16(Wih1[idx], &wi1h[idx], &wi1l[idx]);
  }
  if (idx < 512 * 32) {  // Wih0 zero-padded K=16 -> 32
    const int g = idx >> 5, k = idx & 31;
    const float f = (k < IN_DIM) ? Wih0[g * IN_DIM + k] : 0.0f;
    split_f16(f, &wxh[idx], &wxl[idx]);
  }
}

// ---------------- Layer 0: persistent MFMA recurrent kernel ----------------
// 256 WGs x 512 threads (8 waves). WG owns batches {2w,2w+1} (M-rows 0,1 of a
// padded 16-row MFMA tile; rows 2..15 of C are never read, so ALL lanes read
// A from row (lane&1): 8-lane broadcast, conflict-free, no divergence).
__global__ __launch_bounds__(512, 2) void lstm_l0(
    const float* __restrict__ x,
    const ushort_t* __restrict__ Wh_hi, const ushort_t* __restrict__ Wh_lo,
    const ushort_t* __restrict__ Wx_hi, const ushort_t* __restrict__ Wx_lo,
    const float* __restrict__ bih, const float* __restrict__ bhh,
    float* __restrict__ h1state, float* __restrict__ c1state,
    ushort_t* __restrict__ h1buf, int t0, int Tc)
{
  const int tid  = threadIdx.x;
  const int wg   = blockIdx.x;
  const int lane = tid & 63;
  const int wv   = tid >> 6;      // wave 0..7, owns gates [wv*64, wv*64+64)
  const int row  = lane & 15;     // B-col / C-col
  const int arow = lane & 1;      // broadcast A-row (real batches only)
  const int kq   = lane >> 4;     // k quarter

  // persistent B fragments: 4 N-tiles x (4 h K-tiles + 1 x K-tile), hi+lo fp16
  f16x8 Bh[4][4], Bl[4][4], Bxh[4], Bxl[4];
#pragma unroll
  for (int i = 0; i < 4; ++i) {
    const int col = wv * 64 + i * 16 + row;
#pragma unroll
    for (int kt = 0; kt < 4; ++kt) {
      const int off = col * HDIM + kt * 32 + kq * 8;
      Bh[i][kt] = *(const f16x8*)&Wh_hi[off];
      Bl[i][kt] = *(const f16x8*)&Wh_lo[off];
    }
    const int xoff = col * 32 + kq * 8;
    Bxh[i] = *(const f16x8*)&Wx_hi[xoff];
    Bxl[i] = *(const f16x8*)&Wx_lo[xoff];
  }

  __shared__ __align__(16) ushort_t hfrag[2][136];   // [batch][k] fp16 h
  __shared__ __align__(16) ushort_t xfrag[2][40];    // [batch][k] fp16 x (k>=16 == 0)
  __shared__ __align__(16) float xs[2][64][IN_DIM];  // fp32 x window
  __shared__ __align__(8)  float gs2[G4][2];         // gates x {batch0,batch1}

  const int bb = tid >> 7;   // update-phase batch (tid<256)
  const int j  = tid & 127;  // update-phase hidden idx
  float bz[4] = {0, 0, 0, 0};
  float c = 0.0f, hcur = 0.0f;

  // zero xfrag once: K-pad region [16,32) must stay 0
  for (int idx = tid; idx < 2 * 40; idx += 512) ((ushort_t*)xfrag)[idx] = 0;
  // stage initial 64-step x window
  {
    const int tb = t0 & ~63;
    const int sb = tid >> 8;
    const int f  = (tid & 255) * 4;
    const int ts = f >> 4, ii = f & 15;
    *(float4*)&xs[sb][ts][ii] =
        *(const float4*)&x[((size_t)(wg * 2 + sb) * T_SEQ + (tb + ts)) * IN_DIM + ii];
  }
  __syncthreads();
  if (tid < 256) {
#pragma unroll
    for (int q = 0; q < 4; ++q) bz[q] = bih[q * 128 + j] + bhh[q * 128 + j];
    const int bg = wg * 2 + bb;
    hcur = h1state[(size_t)bg * HDIM + j];
    c    = c1state[(size_t)bg * HDIM + j];
    hfrag[bb][j] = f16_bits(hcur);
  }
  if (tid < 32) {
    const int b = tid >> 4, k = tid & 15;
    xfrag[b][k] = f16_bits(xs[b][t0 & 63][k]);
  }
  __syncthreads();

  for (int tt = 0; tt < Tc; ++tt) {
    const int t = t0 + tt;
    // ---- MFMA phase: gates = [h; x] . W^T (fp16 2-term) ----
    f32x4 acc[4];
#pragma unroll
    for (int i = 0; i < 4; ++i) acc[i] = (f32x4){0.f, 0.f, 0.f, 0.f};
#pragma unroll
    for (int kt = 0; kt < 4; ++kt) {
      const f16x8 ah = *(const f16x8*)&hfrag[arow][kt * 32 + kq * 8];
#pragma unroll
      for (int i = 0; i < 4; ++i) acc[i] = MFMA16(ah, Bh[i][kt], acc[i]);
#pragma unroll
      for (int i = 0; i < 4; ++i) acc[i] = MFMA16(ah, Bl[i][kt], acc[i]);
    }
    {
      const f16x8 ax = *(const f16x8*)&xfrag[arow][kq * 8];
#pragma unroll
      for (int i = 0; i < 4; ++i) acc[i] = MFMA16(ax, Bxh[i], acc[i]);
#pragma unroll
      for (int i = 0; i < 4; ++i) acc[i] = MFMA16(ax, Bxl[i], acc[i]);
    }
    if (kq == 0) {  // C rows 0,1 = batches
#pragma unroll
      for (int i = 0; i < 4; ++i) {
        const int g = wv * 64 + i * 16 + row;
        float2 v;
        v.x = acc[i][0];
        v.y = acc[i][1];
        *(float2*)&gs2[g][0] = v;
      }
    }
    __syncthreads();

    // ---- update phase ----
    const bool needStage = (((t + 1) & 63) == 0) && (t + 1 < T_SEQ);
    if (tid < 256) {
      const float zi = gs2[j][bb]       + bz[0];
      const float zf = gs2[128 + j][bb] + bz[1];
      const float zg = gs2[256 + j][bb] + bz[2];
      const float zo = gs2[384 + j][bb] + bz[3];
      const float ig = sigf(zi), fg = sigf(zf);
      const float gg = tanhf_fast(zg), og = sigf(zo);
      c = fg * c + ig * gg;
      hcur = og * tanhf_fast(c);
      const ushort_t hb = f16_bits(hcur);
      hfrag[bb][j] = hb;
      h1buf[((size_t)tt * NBATCH + (wg * 2 + bb)) * HDIM + j] = hb;
    } else if (needStage) {
      const int u  = tid - 256;
      const int tb = t + 1;
#pragma unroll
      for (int q = 0; q < 2; ++q) {
        const int f  = (q * 256 + u) * 4;
        const int sb = f >> 10;
        const int ff = f & 1023;
        const int ts = ff >> 4, ii = ff & 15;
        *(float4*)&xs[sb][ts][ii] =
            *(const float4*)&x[((size_t)(wg * 2 + sb) * T_SEQ + (tb + ts)) * IN_DIM + ii];
      }
    }
    if (needStage) __syncthreads();
    if (tid < 32 && tt + 1 < Tc) {
      const int b = tid >> 4, k = tid & 15;
      xfrag[b][k] = f16_bits(xs[b][(t + 1) & 63][k]);
    }
    __syncthreads();
  }

  if (tid < 256) {
    const int bg = wg * 2 + bb;
    h1state[(size_t)bg * HDIM + j] = hcur;
    c1state[(size_t)bg * HDIM + j] = c;
  }
}

// ---------------- gx1 GEMM: fp16 MFMA, zero-LDS ----------------
// grid (M/128, 8); 256 threads = 4 waves (2 m-halves x 2 n-halves).
// Per wave: 64M x 32N, K=128 in 4 tiles x 2 W-terms = 32 MFMAs.
// A-fragments read directly from global (h1buf fp16, L2/L3-resident).
__global__ __launch_bounds__(256, 2) void gemm_gx1(
    const ushort_t* __restrict__ h1buf,
    const ushort_t* __restrict__ Wh, const ushort_t* __restrict__ Wl,
    const float* __restrict__ bih1, const float* __restrict__ bhh1,
    float* __restrict__ gx1buf)
{
  const int u    = threadIdx.x;
  const int lane = u & 63;
  const int wv   = u >> 6;
  const int row  = lane & 15;
  const int kq   = lane >> 4;
  const size_t m0 = (size_t)blockIdx.x * 128 + (wv >> 1) * 64;
  const int    n0 = blockIdx.y * 64 + (wv & 1) * 32;

  // B fragments: 2 n-frags x 4 k-tiles x {hi,lo}
  f16x8 Bh[2][4], Bl[2][4];
  float bias[2];
#pragma unroll
  for (int nf = 0; nf < 2; ++nf) {
    const int col = n0 + nf * 16 + row;
#pragma unroll
    for (int kt = 0; kt < 4; ++kt) {
      const int off = col * HDIM + kt * 32 + kq * 8;
      Bh[nf][kt] = *(const f16x8*)&Wh[off];
      Bl[nf][kt] = *(const f16x8*)&Wl[off];
    }
    bias[nf] = bih1[col] + bhh1[col];
  }

  f32x4 acc[4][2];
#pragma unroll
  for (int mi = 0; mi < 4; ++mi)
#pragma unroll
    for (int nf = 0; nf < 2; ++nf) acc[mi][nf] = (f32x4){0.f, 0.f, 0.f, 0.f};

#pragma unroll
  for (int kt = 0; kt < 4; ++kt) {
#pragma unroll
    for (int mi = 0; mi < 4; ++mi) {
      const f16x8 a =
          *(const f16x8*)&h1buf[(m0 + mi * 16 + row) * HDIM + kt * 32 + kq * 8];
      acc[mi][0] = MFMA16(a, Bh[0][kt], acc[mi][0]);
      acc[mi][1] = MFMA16(a, Bh[1][kt], acc[mi][1]);
      acc[mi][0] = MFMA16(a, Bl[0][kt], acc[mi][0]);
      acc[mi][1] = MFMA16(a, Bl[1][kt], acc[mi][1]);
    }
  }

  // epilogue: C col = lane&15, row = kq*4 + reg
#pragma unroll
  for (int mi = 0; mi < 4; ++mi) {
#pragma unroll
    for (int nf = 0; nf < 2; ++nf) {
      const int col = n0 + nf * 16 + row;
#pragma unroll
      for (int r = 0; r < 4; ++r) {
        const size_t m = m0 + mi * 16 + kq * 4 + r;
        gx1buf[m * G4 + col] = acc[mi][nf][r] + bias[nf];
      }
    }
  }
}

// ---------------- Layer 1 (MFMA) + fused FC ----------------
__global__ __launch_bounds__(512, 2) void lstm_l1(
    const float* __restrict__ gx1buf,
    const ushort_t* __restrict__ Wh_hi, const ushort_t* __restrict__ Wh_lo,
    const float* __restrict__ Wfc, const float* __restrict__ bfc,
    float* __restrict__ h2state, float* __restrict__ c2state,
    float* __restrict__ out, int t0, int Tc)
{
  const int tid  = threadIdx.x;
  const int wg   = blockIdx.x;
  const int lane = tid & 63;
  const int wv   = tid >> 6;
  const int row  = lane & 15;
  const int arow = lane & 1;
  const int kq   = lane >> 4;

  f16x8 Bh[4][4], Bl[4][4];
#pragma unroll
  for (int i = 0; i < 4; ++i) {
    const int col = wv * 64 + i * 16 + row;
#pragma unroll
    for (int kt = 0; kt < 4; ++kt) {
      const int off = col * HDIM + kt * 32 + kq * 8;
      Bh[i][kt] = *(const f16x8*)&Wh_hi[off];
      Bl[i][kt] = *(const f16x8*)&Wh_lo[off];
    }
  }

  __shared__ __align__(16) ushort_t hfrag[2][136];
  __shared__ __align__(8)  float gs2[G4][2];
  __shared__ float pl[4];

  const int bb = tid >> 7;
  const int j  = tid & 127;
  float c = 0.0f, hcur = 0.0f, wfc = 0.0f;
  const float bfcv = bfc[0];

  float zc[4] = {0, 0, 0, 0};
  if (tid < 256) {
    const int bg = wg * 2 + bb;
    hcur = h2state[(size_t)bg * HDIM + j];
    c    = c2state[(size_t)bg * HDIM + j];
    wfc  = Wfc[j];
    hfrag[bb][j] = f16_bits(hcur);
#pragma unroll
    for (int q = 0; q < 4; ++q)
      zc[q] = gx1buf[((size_t)0 * NBATCH + wg * 2 + bb) * G4 + q * 128 + j];
  }
  __syncthreads();

  for (int tt = 0; tt < Tc; ++tt) {
    f32x4 acc[4];
#pragma unroll
    for (int i = 0; i < 4; ++i) acc[i] = (f32x4){0.f, 0.f, 0.f, 0.f};
#pragma unroll
    for (int kt = 0; kt < 4; ++kt) {
      const f16x8 ah = *(const f16x8*)&hfrag[arow][kt * 32 + kq * 8];
#pragma unroll
      for (int i = 0; i < 4; ++i) acc[i] = MFMA16(ah, Bh[i][kt], acc[i]);
#pragma unroll
      for (int i = 0; i < 4; ++i) acc[i] = MFMA16(ah, Bl[i][kt], acc[i]);
    }
    if (kq == 0) {
#pragma unroll
      for (int i = 0; i < 4; ++i) {
        const int g = wv * 64 + i * 16 + row;
        float2 v;
        v.x = acc[i][0];
        v.y = acc[i][1];
        *(float2*)&gs2[g][0] = v;
      }
    }
    __syncthreads();

    if (tid < 256) {
      const float zi = gs2[j][bb]       + zc[0];
      const float zf = gs2[128 + j][bb] + zc[1];
      const float zg = gs2[256 + j][bb] + zc[2];
      const float zo = gs2[384 + j][bb] + zc[3];
      const float ig = sigf(zi), fg = sigf(zf);
      const float gg = tanhf_fast(zg), og = sigf(zo);
      c = fg * c + ig * gg;
      hcur = og * tanhf_fast(c);
      hfrag[bb][j] = f16_bits(hcur);
      if (tt + 1 < Tc) {
#pragma unroll
        for (int q = 0; q < 4; ++q)
          zc[q] = gx1buf[((size_t)(tt + 1) * NBATCH + wg * 2 + bb) * G4 + q * 128 + j];
      }
      float p = fmaxf(hcur, 0.0f) * wfc;
#pragma unroll
      for (int off = 32; off; off >>= 1) p += __shfl_down(p, off);
      if ((tid & 63) == 0) pl[tid >> 6] = p;
    }
    __syncthreads();

    if (tid < 2) {
      const float o = pl[2 * tid] + pl[2 * tid + 1] + bfcv;
      out[(size_t)(wg * 2 + tid) * T_SEQ + (t0 + tt)] = fmaxf(o, 0.0f);
    }
  }

  if (tid < 256) {
    const int bg = wg * 2 + bb;
    h2state[(size_t)bg * HDIM + j] = hcur;
    c2state[(size_t)bg * HDIM + j] = c;
  }
}

extern "C" void kernel_launch(void* const* d_in, const int* in_sizes, int n_in,
                              void* d_out, int out_size, void* d_ws, size_t ws_size,
                              hipStream_t stream)
{
  const float* x    = (const float*)d_in[0];
  const float* Wih0 = (const float*)d_in[1];
  const float* Whh0 = (const float*)d_in[2];
  const float* bih0 = (const float*)d_in[3];
  const float* bhh0 = (const float*)d_in[4];
  const float* Wih1 = (const float*)d_in[5];
  const float* Whh1 = (const float*)d_in[6];
  const float* bih1 = (const float*)d_in[7];
  const float* bhh1 = (const float*)d_in[8];
  const float* Wfc  = (const float*)d_in[9];
  const float* bfc  = (const float*)d_in[10];
  float* out = (float*)d_out;

  const size_t stateN = (size_t)NBATCH * HDIM;  // 65536
  float* h1s = (float*)d_ws;
  float* c1s = h1s + stateN;
  float* h2s = c1s + stateN;
  float* c2s = h2s + stateN;
  ushort_t* w0h  = (ushort_t*)(c2s + stateN);
  ushort_t* w0l  = w0h + stateN;
  ushort_t* w1h  = w0l + stateN;
  ushort_t* w1l  = w1h + stateN;
  ushort_t* wxh  = w1l + stateN;
  ushort_t* wxl  = wxh + 512 * 32;
  ushort_t* wi1h = wxl + 512 * 32;
  ushort_t* wi1l = wi1h + stateN;
  ushort_t* h1buf = wi1l + stateN;
  const size_t fixedBytes = 4 * stateN * sizeof(float) +
                            (6 * stateN + 2 * 512 * 32) * sizeof(ushort_t);

  int Tc = 128;
  while (Tc > 1) {
    const size_t need = fixedBytes +
        (size_t)Tc * NBATCH * (HDIM * sizeof(ushort_t) + G4 * sizeof(float));
    if (need <= ws_size) break;
    Tc >>= 1;
  }
  float* gx1buf = (float*)(h1buf + (size_t)Tc * NBATCH * HDIM);

  hipLaunchKernelGGL(prep_weights, dim3(256), dim3(256), 0, stream,
                     Whh0, Whh1, Wih0, Wih1,
                     w0h, w0l, w1h, w1l, wxh, wxl, wi1h, wi1l);
  (void)hipMemsetAsync(d_ws, 0, 4 * stateN * sizeof(float), stream);

  for (int t0 = 0; t0 < T_SEQ; t0 += Tc) {
    hipLaunchKernelGGL(lstm_l0, dim3(NBATCH / 2), dim3(512), 0, stream,
                       x, w0h, w0l, wxh, wxl, bih0, bhh0, h1s, c1s, h1buf, t0, Tc);
    hipLaunchKernelGGL(gemm_gx1, dim3(Tc * NBATCH / 128, G4 / 64), dim3(256),
                       0, stream,
                       h1buf, wi1h, wi1l, bih1, bhh1, gx1buf);
    hipLaunchKernelGGL(lstm_l1, dim3(NBATCH / 2), dim3(512), 0, stream,
                       gx1buf, w1h, w1l, Wfc, bfc, h2s, c2s, out, t0, Tc);
  }
}

// Round 8
// 2627.652 us; speedup vs baseline: 1.4475x; 1.0247x over previous
//
#include <hip/hip_runtime.h>

#define T_SEQ  1024
#define NBATCH 512
#define IN_DIM 16
#define HDIM   128
#define G4     (4 * HDIM)

typedef unsigned short ushort_t;
typedef __attribute__((ext_vector_type(8))) _Float16 f16x8;
typedef __attribute__((ext_vector_type(4))) float f32x4;

#define MFMA16(a, b, c) __builtin_amdgcn_mfma_f32_16x16x32_f16((a), (b), (c), 0, 0, 0)

__device__ __forceinline__ float sigf(float x) {
  return __builtin_amdgcn_rcpf(1.0f + __expf(-x));
}
__device__ __forceinline__ float tanhf_fast(float x) {
  return 1.0f - 2.0f * __builtin_amdgcn_rcpf(1.0f + __expf(2.0f * x));
}
__device__ __forceinline__ ushort_t f16_bits(float f) {
  const _Float16 h = (_Float16)f;
  return __builtin_bit_cast(unsigned short, h);
}
__device__ __forceinline__ void split_f16(float f, ushort_t* hi, ushort_t* lo) {
  const _Float16 h = (_Float16)f;
  *hi = __builtin_bit_cast(unsigned short, h);
  const _Float16 l = (_Float16)(f - (float)h);
  *lo = __builtin_bit_cast(unsigned short, l);
}

// ---------------- prep: split weights into fp16 hi/lo ----------------
__global__ __launch_bounds__(256) void prep_weights(
    const float* __restrict__ Whh0, const float* __restrict__ Whh1,
    const float* __restrict__ Wih0, const float* __restrict__ Wih1,
    ushort_t* __restrict__ w0h, ushort_t* __restrict__ w0l,
    ushort_t* __restrict__ w1h, ushort_t* __restrict__ w1l,
    ushort_t* __restrict__ wxh, ushort_t* __restrict__ wxl,
    ushort_t* __restrict__ wi1h, ushort_t* __restrict__ wi1l)
{
  const int idx = blockIdx.x * 256 + threadIdx.x;
  if (idx < 512 * HDIM) {
    split_f16(Whh0[idx], &w0h[idx], &w0l[idx]);
    split_f16(Whh1[idx], &w1h[idx], &w1l[idx]);
    split_f16(Wih1[idx], &wi1h[idx], &wi1l[idx]);
  }
  if (idx < 512 * 32) {  // Wih0 zero-padded K=16 -> 32
    const int g = idx >> 5, k = idx & 31;
    const float f = (k < IN_DIM) ? Wih0[g * IN_DIM + k] : 0.0f;
    split_f16(f, &wxh[idx], &wxl[idx]);
  }
}

// ---------------- Layer 0: persistent MFMA recurrent, in-lane update -------
// 256 WGs x 512 threads. WG owns batches {2w,2w+1} (C rows 0,1 => kq==0 lanes,
// regs 0,1). Gate columns PERMUTED: wave wv, N-tile i covers gates
// i*128 + wv*16 + col, so a kq==0 lane holds all 4 gate types for hidden unit
// j = wv*16+lane and both batches -> LSTM update is fully in-lane.
// One barrier per step; hfrag double-buffered.
__global__ __launch_bounds__(512, 2) void lstm_l0(
    const float* __restrict__ x,
    const ushort_t* __restrict__ Wh_hi, const ushort_t* __restrict__ Wh_lo,
    const ushort_t* __restrict__ Wx_hi, const ushort_t* __restrict__ Wx_lo,
    const float* __restrict__ bih, const float* __restrict__ bhh,
    float* __restrict__ h1state, float* __restrict__ c1state,
    ushort_t* __restrict__ h1buf, int t0, int Tc)
{
  const int tid  = threadIdx.x;
  const int wg   = blockIdx.x;
  const int lane = tid & 63;
  const int wv   = tid >> 6;
  const int row  = lane & 15;
  const int arow = lane & 1;
  const int kq   = lane >> 4;

  // B fragments (permuted gate cols): 4 gate-type tiles x (4 h K + 1 x K), hi/lo
  f16x8 Bh[4][4], Bl[4][4], Bxh[4], Bxl[4];
#pragma unroll
  for (int i = 0; i < 4; ++i) {
    const int g = i * 128 + wv * 16 + row;
#pragma unroll
    for (int kt = 0; kt < 4; ++kt) {
      const int off = g * HDIM + kt * 32 + kq * 8;
      Bh[i][kt] = *(const f16x8*)&Wh_hi[off];
      Bl[i][kt] = *(const f16x8*)&Wh_lo[off];
    }
    const int xoff = g * 32 + kq * 8;
    Bxh[i] = *(const f16x8*)&Wx_hi[xoff];
    Bxl[i] = *(const f16x8*)&Wx_lo[xoff];
  }

  __shared__ __align__(16) ushort_t hfrag[2][2][136];  // [buf][batch][k]
  __shared__ __align__(16) ushort_t xlds[2][128][32];  // fp16 x chunk (k>=16 == 0)

  // stage this chunk's x into LDS as fp16 (once per chunk)
  for (int idx = tid; idx < 2 * Tc * 2; idx += 512) {
    const int sb = idx / (Tc * 2);
    const int r  = idx - sb * (Tc * 2);
    const int ts = r >> 1;
    const int kh = (r & 1) * 8;
    const float* src = &x[((size_t)(wg * 2 + sb) * T_SEQ + t0 + ts) * IN_DIM + kh];
    const float4 v0 = *(const float4*)&src[0];
    const float4 v1 = *(const float4*)&src[4];
    ushort_t* dst = &xlds[sb][ts][kh];
    dst[0] = f16_bits(v0.x); dst[1] = f16_bits(v0.y);
    dst[2] = f16_bits(v0.z); dst[3] = f16_bits(v0.w);
    dst[4] = f16_bits(v1.x); dst[5] = f16_bits(v1.y);
    dst[6] = f16_bits(v1.z); dst[7] = f16_bits(v1.w);
    if (kh == 8) {  // zero the K-pad [16,32)
      *(float4*)&xlds[sb][ts][16] = (float4){0.f, 0.f, 0.f, 0.f};
      *(float4*)&xlds[sb][ts][24] = (float4){0.f, 0.f, 0.f, 0.f};
    }
  }

  const bool upd = (kq == 0);
  const int  j   = wv * 16 + row;
  float bz[4] = {0, 0, 0, 0};
  float c0 = 0, c1 = 0, h0 = 0, h1 = 0;
  if (upd) {
#pragma unroll
    for (int i = 0; i < 4; ++i) bz[i] = bih[i * 128 + j] + bhh[i * 128 + j];
    h0 = h1state[(size_t)(wg * 2 + 0) * HDIM + j];
    c0 = c1state[(size_t)(wg * 2 + 0) * HDIM + j];
    h1 = h1state[(size_t)(wg * 2 + 1) * HDIM + j];
    c1 = c1state[(size_t)(wg * 2 + 1) * HDIM + j];
    hfrag[0][0][j] = f16_bits(h0);
    hfrag[0][1][j] = f16_bits(h1);
  }
  __syncthreads();

  int cur = 0;
  for (int tt = 0; tt < Tc; ++tt) {
    const f16x8 ax = *(const f16x8*)&xlds[arow][tt][kq * 8];
    f32x4 acc[4];
#pragma unroll
    for (int i = 0; i < 4; ++i) acc[i] = (f32x4){0.f, 0.f, 0.f, 0.f};
#pragma unroll
    for (int kt = 0; kt < 4; ++kt) {
      const f16x8 ah = *(const f16x8*)&hfrag[cur][arow][kt * 32 + kq * 8];
#pragma unroll
      for (int i = 0; i < 4; ++i) acc[i] = MFMA16(ah, Bh[i][kt], acc[i]);
#pragma unroll
      for (int i = 0; i < 4; ++i) acc[i] = MFMA16(ah, Bl[i][kt], acc[i]);
    }
#pragma unroll
    for (int i = 0; i < 4; ++i) acc[i] = MFMA16(ax, Bxh[i], acc[i]);
#pragma unroll
    for (int i = 0; i < 4; ++i) acc[i] = MFMA16(ax, Bxl[i], acc[i]);

    if (upd) {
      const float ig0 = sigf(acc[0][0] + bz[0]);
      const float fg0 = sigf(acc[1][0] + bz[1]);
      const float gg0 = tanhf_fast(acc[2][0] + bz[2]);
      const float og0 = sigf(acc[3][0] + bz[3]);
      c0 = fg0 * c0 + ig0 * gg0;
      h0 = og0 * tanhf_fast(c0);
      const float ig1 = sigf(acc[0][1] + bz[0]);
      const float fg1 = sigf(acc[1][1] + bz[1]);
      const float gg1 = tanhf_fast(acc[2][1] + bz[2]);
      const float og1 = sigf(acc[3][1] + bz[3]);
      c1 = fg1 * c1 + ig1 * gg1;
      h1 = og1 * tanhf_fast(c1);
      const ushort_t hb0 = f16_bits(h0);
      const ushort_t hb1 = f16_bits(h1);
      hfrag[cur ^ 1][0][j] = hb0;
      hfrag[cur ^ 1][1][j] = hb1;
      h1buf[((size_t)tt * NBATCH + wg * 2 + 0) * HDIM + j] = hb0;
      h1buf[((size_t)tt * NBATCH + wg * 2 + 1) * HDIM + j] = hb1;
    }
    __syncthreads();
    cur ^= 1;
  }

  if (upd) {
    h1state[(size_t)(wg * 2 + 0) * HDIM + j] = h0;
    c1state[(size_t)(wg * 2 + 0) * HDIM + j] = c0;
    h1state[(size_t)(wg * 2 + 1) * HDIM + j] = h1;
    c1state[(size_t)(wg * 2 + 1) * HDIM + j] = c1;
  }
}

// ---------------- gx1 GEMM: fp16 MFMA, zero-LDS (unchanged) ----------------
__global__ __launch_bounds__(256, 2) void gemm_gx1(
    const ushort_t* __restrict__ h1buf,
    const ushort_t* __restrict__ Wh, const ushort_t* __restrict__ Wl,
    const float* __restrict__ bih1, const float* __restrict__ bhh1,
    float* __restrict__ gx1buf)
{
  const int u    = threadIdx.x;
  const int lane = u & 63;
  const int wv   = u >> 6;
  const int row  = lane & 15;
  const int kq   = lane >> 4;
  const size_t m0 = (size_t)blockIdx.x * 128 + (wv >> 1) * 64;
  const int    n0 = blockIdx.y * 64 + (wv & 1) * 32;

  f16x8 Bh[2][4], Bl[2][4];
  float bias[2];
#pragma unroll
  for (int nf = 0; nf < 2; ++nf) {
    const int col = n0 + nf * 16 + row;
#pragma unroll
    for (int kt = 0; kt < 4; ++kt) {
      const int off = col * HDIM + kt * 32 + kq * 8;
      Bh[nf][kt] = *(const f16x8*)&Wh[off];
      Bl[nf][kt] = *(const f16x8*)&Wl[off];
    }
    bias[nf] = bih1[col] + bhh1[col];
  }

  f32x4 acc[4][2];
#pragma unroll
  for (int mi = 0; mi < 4; ++mi)
#pragma unroll
    for (int nf = 0; nf < 2; ++nf) acc[mi][nf] = (f32x4){0.f, 0.f, 0.f, 0.f};

#pragma unroll
  for (int kt = 0; kt < 4; ++kt) {
#pragma unroll
    for (int mi = 0; mi < 4; ++mi) {
      const f16x8 a =
          *(const f16x8*)&h1buf[(m0 + mi * 16 + row) * HDIM + kt * 32 + kq * 8];
      acc[mi][0] = MFMA16(a, Bh[0][kt], acc[mi][0]);
      acc[mi][1] = MFMA16(a, Bh[1][kt], acc[mi][1]);
      acc[mi][0] = MFMA16(a, Bl[0][kt], acc[mi][0]);
      acc[mi][1] = MFMA16(a, Bl[1][kt], acc[mi][1]);
    }
  }

#pragma unroll
  for (int mi = 0; mi < 4; ++mi) {
#pragma unroll
    for (int nf = 0; nf < 2; ++nf) {
      const int col = n0 + nf * 16 + row;
#pragma unroll
      for (int r = 0; r < 4; ++r) {
        const size_t m = m0 + mi * 16 + kq * 4 + r;
        gx1buf[m * G4 + col] = acc[mi][nf][r] + bias[nf];
      }
    }
  }
}

// ---------------- Layer 1: in-lane update + fused FC ----------------
__global__ __launch_bounds__(512, 2) void lstm_l1(
    const float* __restrict__ gx1buf,
    const ushort_t* __restrict__ Wh_hi, const ushort_t* __restrict__ Wh_lo,
    const float* __restrict__ Wfc, const float* __restrict__ bfc,
    float* __restrict__ h2state, float* __restrict__ c2state,
    float* __restrict__ out, int t0, int Tc)
{
  const int tid  = threadIdx.x;
  const int wg   = blockIdx.x;
  const int lane = tid & 63;
  const int wv   = tid >> 6;
  const int row  = lane & 15;
  const int arow = lane & 1;
  const int kq   = lane >> 4;

  f16x8 Bh[4][4], Bl[4][4];
#pragma unroll
  for (int i = 0; i < 4; ++i) {
    const int g = i * 128 + wv * 16 + row;
#pragma unroll
    for (int kt = 0; kt < 4; ++kt) {
      const int off = g * HDIM + kt * 32 + kq * 8;
      Bh[i][kt] = *(const f16x8*)&Wh_hi[off];
      Bl[i][kt] = *(const f16x8*)&Wh_lo[off];
    }
  }

  __shared__ __align__(16) ushort_t hfrag[2][2][136];
  __shared__ float pl[2][8][2];

  const bool upd = (kq == 0);
  const int  j   = wv * 16 + row;
  float c0 = 0, c1 = 0, h0 = 0, h1 = 0, wfc = 0;
  const float bfcv = bfc[0];
  if (upd) {
    h0 = h2state[(size_t)(wg * 2 + 0) * HDIM + j];
    c0 = c2state[(size_t)(wg * 2 + 0) * HDIM + j];
    h1 = h2state[(size_t)(wg * 2 + 1) * HDIM + j];
    c1 = c2state[(size_t)(wg * 2 + 1) * HDIM + j];
    wfc = Wfc[j];
    hfrag[0][0][j] = f16_bits(h0);
    hfrag[0][1][j] = f16_bits(h1);
  }
  __syncthreads();

  int cur = 0;
  for (int tt = 0; tt < Tc; ++tt) {
    // gate-input loads for this step (issued before MFMAs, consumed after)
    float zc0[4], zc1[4];
    if (upd) {
      const float* g0 = &gx1buf[((size_t)tt * NBATCH + wg * 2 + 0) * G4];
      const float* g1 = &gx1buf[((size_t)tt * NBATCH + wg * 2 + 1) * G4];
#pragma unroll
      for (int i = 0; i < 4; ++i) {
        zc0[i] = g0[i * 128 + j];
        zc1[i] = g1[i * 128 + j];
      }
    }

    f32x4 acc[4];
#pragma unroll
    for (int i = 0; i < 4; ++i) acc[i] = (f32x4){0.f, 0.f, 0.f, 0.f};
#pragma unroll
    for (int kt = 0; kt < 4; ++kt) {
      const f16x8 ah = *(const f16x8*)&hfrag[cur][arow][kt * 32 + kq * 8];
#pragma unroll
      for (int i = 0; i < 4; ++i) acc[i] = MFMA16(ah, Bh[i][kt], acc[i]);
#pragma unroll
      for (int i = 0; i < 4; ++i) acc[i] = MFMA16(ah, Bl[i][kt], acc[i]);
    }

    if (upd) {
      const float ig0 = sigf(acc[0][0] + zc0[0]);
      const float fg0 = sigf(acc[1][0] + zc0[1]);
      const float gg0 = tanhf_fast(acc[2][0] + zc0[2]);
      const float og0 = sigf(acc[3][0] + zc0[3]);
      c0 = fg0 * c0 + ig0 * gg0;
      h0 = og0 * tanhf_fast(c0);
      const float ig1 = sigf(acc[0][1] + zc1[0]);
      const float fg1 = sigf(acc[1][1] + zc1[1]);
      const float gg1 = tanhf_fast(acc[2][1] + zc1[2]);
      const float og1 = sigf(acc[3][1] + zc1[3]);
      c1 = fg1 * c1 + ig1 * gg1;
      h1 = og1 * tanhf_fast(c1);
      hfrag[cur ^ 1][0][j] = f16_bits(h0);
      hfrag[cur ^ 1][1][j] = f16_bits(h1);
      // fused FC partials: reduce relu(h)*wfc over the 16 lanes
      float p0 = fmaxf(h0, 0.0f) * wfc;
      float p1 = fmaxf(h1, 0.0f) * wfc;
#pragma unroll
      for (int m = 1; m < 16; m <<= 1) {
        p0 += __shfl_xor(p0, m, 64);
        p1 += __shfl_xor(p1, m, 64);
      }
      if (row == 0) {
        pl[cur][wv][0] = p0;
        pl[cur][wv][1] = p1;
      }
    }
    __syncthreads();

    if (tid < 2) {
      float s = bfcv;
#pragma unroll
      for (int w = 0; w < 8; ++w) s += pl[cur][w][tid];
      out[(size_t)(wg * 2 + tid) * T_SEQ + t0 + tt] = fmaxf(s, 0.0f);
    }
    cur ^= 1;
  }

  if (upd) {
    h2state[(size_t)(wg * 2 + 0) * HDIM + j] = h0;
    c2state[(size_t)(wg * 2 + 0) * HDIM + j] = c0;
    h2state[(size_t)(wg * 2 + 1) * HDIM + j] = h1;
    c2state[(size_t)(wg * 2 + 1) * HDIM + j] = c1;
  }
}

extern "C" void kernel_launch(void* const* d_in, const int* in_sizes, int n_in,
                              void* d_out, int out_size, void* d_ws, size_t ws_size,
                              hipStream_t stream)
{
  const float* x    = (const float*)d_in[0];
  const float* Wih0 = (const float*)d_in[1];
  const float* Whh0 = (const float*)d_in[2];
  const float* bih0 = (const float*)d_in[3];
  const float* bhh0 = (const float*)d_in[4];
  const float* Wih1 = (const float*)d_in[5];
  const float* Whh1 = (const float*)d_in[6];
  const float* bih1 = (const float*)d_in[7];
  const float* bhh1 = (const float*)d_in[8];
  const float* Wfc  = (const float*)d_in[9];
  const float* bfc  = (const float*)d_in[10];
  float* out = (float*)d_out;

  const size_t stateN = (size_t)NBATCH * HDIM;  // 65536
  float* h1s = (float*)d_ws;
  float* c1s = h1s + stateN;
  float* h2s = c1s + stateN;
  float* c2s = h2s + stateN;
  ushort_t* w0h  = (ushort_t*)(c2s + stateN);
  ushort_t* w0l  = w0h + stateN;
  ushort_t* w1h  = w0l + stateN;
  ushort_t* w1l  = w1h + stateN;
  ushort_t* wxh  = w1l + stateN;
  ushort_t* wxl  = wxh + 512 * 32;
  ushort_t* wi1h = wxl + 512 * 32;
  ushort_t* wi1l = wi1h + stateN;
  ushort_t* h1buf = wi1l + stateN;
  const size_t fixedBytes = 4 * stateN * sizeof(float) +
                            (6 * stateN + 2 * 512 * 32) * sizeof(ushort_t);

  int Tc = 128;
  while (Tc > 1) {
    const size_t need = fixedBytes +
        (size_t)Tc * NBATCH * (HDIM * sizeof(ushort_t) + G4 * sizeof(float));
    if (need <= ws_size) break;
    Tc >>= 1;
  }
  float* gx1buf = (float*)(h1buf + (size_t)Tc * NBATCH * HDIM);

  hipLaunchKernelGGL(prep_weights, dim3(256), dim3(256), 0, stream,
                     Whh0, Whh1, Wih0, Wih1,
                     w0h, w0l, w1h, w1l, wxh, wxl, wi1h, wi1l);
  (void)hipMemsetAsync(d_ws, 0, 4 * stateN * sizeof(float), stream);

  for (int t0 = 0; t0 < T_SEQ; t0 += Tc) {
    hipLaunchKernelGGL(lstm_l0, dim3(NBATCH / 2), dim3(512), 0, stream,
                       x, w0h, w0l, wxh, wxl, bih0, bhh0, h1s, c1s, h1buf, t0, Tc);
    hipLaunchKernelGGL(gemm_gx1, dim3(Tc * NBATCH / 128, G4 / 64), dim3(256),
                       0, stream,
                       h1buf, wi1h, wi1l, bih1, bhh1, gx1buf);
    hipLaunchKernelGGL(lstm_l1, dim3(NBATCH / 2), dim3(512), 0, stream,
                       gx1buf, w1h, w1l, Wfc, bfc, h2s, c2s, out, t0, Tc);
  }
}